// Round 7
// baseline (133.813 us; speedup 1.0000x reference)
//
#include <hip/hip_runtime.h>
#include <math.h>

#define DCH  128    // channel dim
#define NPIX 4096   // H*W
#define BATCH 8
#define BN   (BATCH * NPIX)

typedef float v2f __attribute__((ext_vector_type(2)));

// ---------------------------------------------------------------------------
// OCP e4m3fn helpers: HW cvt on gfx950, exact software fallback otherwise.
// The builtins' word-select args must be COMPILE-TIME constants -> template.
// ---------------------------------------------------------------------------
#if __has_builtin(__builtin_amdgcn_cvt_pk_fp8_f32)
#define HAVE_HW_FP8_ENC 1
#endif
#if __has_builtin(__builtin_amdgcn_cvt_pk_f32_fp8)
#define HAVE_HW_FP8_DEC 1
#endif

__device__ inline unsigned f32_to_fp8_sw(float x) {
    unsigned s = (__float_as_uint(x) >> 24) & 0x80u;
    float ax = fabsf(x);
    if (!(ax > 0.f)) return s;
    if (ax >= 448.f) return s | 0x7Eu;
    int e; frexpf(ax, &e);                       // ax = m*2^e, m in [0.5,1)
    if (e >= -5) {                               // normal: 1.mmm * 2^(e-1)
        int q = (int)rintf(ldexpf(ax, 4 - e));   // in [8,16]
        if (q == 16) { q = 8; ++e; }
        if (e + 6 >= 16) return s | 0x7Eu;
        return s | ((unsigned)(e + 6) << 3) | (unsigned)(q - 8);
    } else {                                     // subnormal: m * 2^-9
        int q = (int)rintf(ldexpf(ax, 9));
        if (q >= 8) return s | (1u << 3);
        return s | (unsigned)q;
    }
}

__device__ inline float fp8_to_f32_sw(unsigned b) {
    unsigned s = b >> 7, e = (b >> 3) & 0xFu, m = b & 7u;
    float v = (e == 0) ? (float)m * 0.001953125f          // m * 2^-9
                       : ldexpf((float)(8u + m), (int)e - 10);
    return s ? -v : v;
}

// pack floats (a,b) as 2 fp8 into the low/high 16 bits of `old`
template <bool HI>
__device__ inline unsigned enc_pair(float a, float b, unsigned old) {
#ifdef HAVE_HW_FP8_ENC
    return (unsigned)__builtin_amdgcn_cvt_pk_fp8_f32(a, b, (int)old, HI);
#else
    unsigned lo = f32_to_fp8_sw(a) | (f32_to_fp8_sw(b) << 8);
    return HI ? ((old & 0x0000FFFFu) | (lo << 16))
              : ((old & 0xFFFF0000u) | lo);
#endif
}

// decode 2 fp8 from low/high 16 bits of v
template <bool HI>
__device__ inline v2f dec_pair(unsigned v) {
#ifdef HAVE_HW_FP8_DEC
    return __builtin_amdgcn_cvt_pk_f32_fp8((int)v, HI);
#else
    unsigned h = HI ? (v >> 16) : (v & 0xFFFFu);
    v2f r; r.x = fp8_to_f32_sw(h & 0xFFu); r.y = fp8_to_f32_sw((h >> 8) & 0xFFu);
    return r;
#endif
}

// ---------------------------------------------------------------------------
// Kernel 1: L2-normalize over channels (fp32 math), write transposed
// (B*N, D) fp8-e4m3 layout: one 128B row (= one cache line) per pixel.
// 256-thread block = 64 pixels x 4 channel-quarters, one pass.
// ---------------------------------------------------------------------------
__global__ void stego_normalize6(const float* __restrict__ feat,
                                 unsigned char* __restrict__ fnorm) {
    int lp = threadIdx.x & 63;        // pixel within block
    int q  = threadIdx.x >> 6;        // channel quarter 0..3
    int p  = blockIdx.x * 64 + lp;    // global pixel id (BN/64 = 512 blocks)
    int b  = p >> 12;                 // p / NPIX
    int n  = p & (NPIX - 1);
    const float* base = feat + ((size_t)b * DCH + q * 32) * NPIX + n;

    float vals[32];
    float s = 0.f;
#pragma unroll
    for (int d = 0; d < 32; ++d) {
        float v = base[(size_t)d * NPIX];   // lanes consecutive n -> coalesced
        vals[d] = v;
        s += v * v;
    }

    __shared__ float part[256];
    part[q * 64 + lp] = s;
    __syncthreads();
    float tot = part[lp] + part[64 + lp] + part[128 + lp] + part[192 + lp];
    float inv = 1.0f / fmaxf(sqrtf(tot), 1e-12f);

    unsigned pk[8];
#pragma unroll
    for (int k = 0; k < 8; ++k) {
        unsigned v = 0;
        v = enc_pair<false>(vals[4 * k + 0] * inv, vals[4 * k + 1] * inv, v);
        v = enc_pair<true>(vals[4 * k + 2] * inv, vals[4 * k + 3] * inv, v);
        pk[k] = v;
    }
    uint4* outp = (uint4*)(fnorm + (size_t)p * DCH + q * 32);
    outp[0] = make_uint4(pk[0], pk[1], pk[2], pk[3]);
    outp[1] = make_uint4(pk[4], pk[5], pk[6], pk[7]);
}

// ---------------------------------------------------------------------------
// Kernel 2: 8 lanes per pair; each lane loads ONE uint4 (16 fp8) per vector,
// so a pair-vector is exactly one 128B cache line. xor-shuffle reduce within
// 8 lanes; block sum -> ONE plain atomicAdd to d_out. No fences / acq-rel /
// last-block pattern (R3 post-mortem: agent-scope sync invalidates per-XCD
// L2, 4x regression). Plain relaxed fp32 atomic RMW has no flush semantics.
// ---------------------------------------------------------------------------
__global__ void stego_pair_loss6(const unsigned char* __restrict__ fnorm,
                                 const int* __restrict__ pb, const int* __restrict__ pi,
                                 const int* __restrict__ pj,
                                 const int* __restrict__ nb, const int* __restrict__ ni,
                                 const int* __restrict__ nj,
                                 float* __restrict__ out, int P, float invP) {
    int t = blockIdx.x * blockDim.x + threadIdx.x;
    int pair = t >> 3;
    int sub  = t & 7;
    float dot = 0.f;
    float sgn = 1.f;
    bool active = (pair < 2 * P);
    if (active) {
        int b, i, j;
        if (pair < P) { b = pb[pair]; i = pi[pair]; j = pj[pair]; sgn = -1.f; }
        else { int u = pair - P; b = nb[u]; i = ni[u]; j = nj[u]; }
        const uint4* va = (const uint4*)(fnorm + ((size_t)b * NPIX + i) * DCH);
        const uint4* vb = (const uint4*)(fnorm + ((size_t)b * NPIX + j) * DCH);
        uint4 ua = va[sub];
        uint4 ub = vb[sub];
        const unsigned* au = (const unsigned*)&ua;
        const unsigned* bu = (const unsigned*)&ub;
#pragma unroll
        for (int m = 0; m < 4; ++m) {
            v2f a0 = dec_pair<false>(au[m]);
            v2f a1 = dec_pair<true>(au[m]);
            v2f b0 = dec_pair<false>(bu[m]);
            v2f b1 = dec_pair<true>(bu[m]);
            dot += a0.x * b0.x + a0.y * b0.y + a1.x * b1.x + a1.y * b1.y;
        }
    }
    // reduce dot across the 8 lanes of this pair
    dot += __shfl_xor(dot, 4, 64);
    dot += __shfl_xor(dot, 2, 64);
    dot += __shfl_xor(dot, 1, 64);

    float loss = 0.f;
    if (active && sub == 0) {
        float z = sgn * dot * 10.0f;                              // /TEMPERATURE, signed
        loss = (fmaxf(z, 0.f) + log1pf(expf(-fabsf(z)))) * invP;  // stable softplus
    }
    // loss nonzero only on lanes 0,8,...,56
    loss += __shfl_xor(loss, 8, 64);
    loss += __shfl_xor(loss, 16, 64);
    loss += __shfl_xor(loss, 32, 64);

    __shared__ float red[4];
    int lane = threadIdx.x & 63;
    int wave = threadIdx.x >> 6;
    if (lane == 0) red[wave] = loss;
    __syncthreads();
    if (threadIdx.x == 0)
        atomicAdd(out, red[0] + red[1] + red[2] + red[3]);
}

// ---------------------------------------------------------------------------
// Fallback (ws too small): invnorm-only + strided gathers + atomics.
// ---------------------------------------------------------------------------
__global__ void stego_invnorm(const float* __restrict__ feat,
                              float* __restrict__ invn, int bn) {
    int p = blockIdx.x * blockDim.x + threadIdx.x;
    if (p >= bn) return;
    int b = p / NPIX;
    int n = p - b * NPIX;
    const float* base = feat + (size_t)b * DCH * NPIX + n;
    float sum = 0.f;
#pragma unroll 8
    for (int d = 0; d < DCH; ++d) {
        float v = base[(size_t)d * NPIX];
        sum += v * v;
    }
    invn[p] = 1.0f / fmaxf(sqrtf(sum), 1e-12f);
}

__global__ void stego_pair_loss_strided(const float* __restrict__ feat,
                                        const float* __restrict__ invn,
                                        const int* __restrict__ pb, const int* __restrict__ pi,
                                        const int* __restrict__ pj,
                                        const int* __restrict__ nb, const int* __restrict__ ni,
                                        const int* __restrict__ nj,
                                        float* __restrict__ out, int P, float invP) {
    int t = blockIdx.x * blockDim.x + threadIdx.x;
    float loss = 0.f;
    if (t < 2 * P) {
        int b, i, j;
        float sgn;
        if (t < P) { b = pb[t]; i = pi[t]; j = pj[t]; sgn = -1.f; }
        else { int u = t - P; b = nb[u]; i = ni[u]; j = nj[u]; sgn = 1.f; }
        const float* a = feat + (size_t)b * DCH * NPIX + i;
        const float* c = feat + (size_t)b * DCH * NPIX + j;
        float dot = 0.f;
#pragma unroll 8
        for (int d = 0; d < DCH; ++d)
            dot += a[(size_t)d * NPIX] * c[(size_t)d * NPIX];
        dot *= invn[b * NPIX + i] * invn[b * NPIX + j];
        float z = sgn * dot * 10.0f;
        float sp = fmaxf(z, 0.f) + log1pf(expf(-fabsf(z)));
        loss = sp * invP;
    }
    for (int off = 32; off > 0; off >>= 1)
        loss += __shfl_down(loss, off, 64);
    __shared__ float red[4];
    int lane = threadIdx.x & 63;
    int wave = threadIdx.x >> 6;
    if (lane == 0) red[wave] = loss;
    __syncthreads();
    if (threadIdx.x == 0) {
        float s = red[0] + red[1] + red[2] + red[3];
        atomicAdd(out, s);
    }
}

extern "C" void kernel_launch(void* const* d_in, const int* in_sizes, int n_in,
                              void* d_out, int out_size, void* d_ws, size_t ws_size,
                              hipStream_t stream) {
    const float* feat = (const float*)d_in[0];
    const int* pb = (const int*)d_in[1];
    const int* pi = (const int*)d_in[2];
    const int* pj = (const int*)d_in[3];
    const int* nb = (const int*)d_in[4];
    const int* ni = (const int*)d_in[5];
    const int* nj = (const int*)d_in[6];
    float* out = (float*)d_out;

    const int P = in_sizes[1];
    const float invP = 1.0f / (float)P;

    size_t fnorm_bytes = (size_t)BN * DCH;                    // 4 MB fp8
    int pairThreads = 2 * P * 8;
    int pairBlocks = (pairThreads + 255) / 256;               // 4096 for P=65536

    (void)hipMemsetAsync(d_out, 0, sizeof(float), stream);

    if (ws_size >= fnorm_bytes) {
        unsigned char* fnorm = (unsigned char*)d_ws;
        stego_normalize6<<<BN / 64, 256, 0, stream>>>(feat, fnorm);
        stego_pair_loss6<<<pairBlocks, 256, 0, stream>>>(
            fnorm, pb, pi, pj, nb, ni, nj, out, P, invP);
    } else {
        float* invn = (float*)d_ws;  // BN floats = 128 KB
        stego_invnorm<<<(BN + 255) / 256, 256, 0, stream>>>(feat, invn, BN);
        int total = 2 * P;
        stego_pair_loss_strided<<<(total + 255) / 256, 256, 0, stream>>>(
            feat, invn, pb, pi, pj, nb, ni, nj, out, P, invP);
    }
}

// Round 8
// 88.644 us; speedup vs baseline: 1.5096x; 1.5096x over previous
//
#include <hip/hip_runtime.h>
#include <math.h>

#define DCH  128    // channel dim
#define NPIX 4096   // H*W
#define BATCH 8
#define BN   (BATCH * NPIX)

typedef float v2f __attribute__((ext_vector_type(2)));

// ---------------------------------------------------------------------------
// OCP e4m3fn helpers: HW cvt on gfx950, exact software fallback otherwise.
// The builtins' word-select args must be COMPILE-TIME constants -> template.
// ---------------------------------------------------------------------------
#if __has_builtin(__builtin_amdgcn_cvt_pk_fp8_f32)
#define HAVE_HW_FP8_ENC 1
#endif
#if __has_builtin(__builtin_amdgcn_cvt_pk_f32_fp8)
#define HAVE_HW_FP8_DEC 1
#endif

__device__ inline unsigned f32_to_fp8_sw(float x) {
    unsigned s = (__float_as_uint(x) >> 24) & 0x80u;
    float ax = fabsf(x);
    if (!(ax > 0.f)) return s;
    if (ax >= 448.f) return s | 0x7Eu;
    int e; frexpf(ax, &e);                       // ax = m*2^e, m in [0.5,1)
    if (e >= -5) {                               // normal: 1.mmm * 2^(e-1)
        int q = (int)rintf(ldexpf(ax, 4 - e));   // in [8,16]
        if (q == 16) { q = 8; ++e; }
        if (e + 6 >= 16) return s | 0x7Eu;
        return s | ((unsigned)(e + 6) << 3) | (unsigned)(q - 8);
    } else {                                     // subnormal: m * 2^-9
        int q = (int)rintf(ldexpf(ax, 9));
        if (q >= 8) return s | (1u << 3);
        return s | (unsigned)q;
    }
}

__device__ inline float fp8_to_f32_sw(unsigned b) {
    unsigned s = b >> 7, e = (b >> 3) & 0xFu, m = b & 7u;
    float v = (e == 0) ? (float)m * 0.001953125f          // m * 2^-9
                       : ldexpf((float)(8u + m), (int)e - 10);
    return s ? -v : v;
}

// pack floats (a,b) as 2 fp8 into the low/high 16 bits of `old`
template <bool HI>
__device__ inline unsigned enc_pair(float a, float b, unsigned old) {
#ifdef HAVE_HW_FP8_ENC
    return (unsigned)__builtin_amdgcn_cvt_pk_fp8_f32(a, b, (int)old, HI);
#else
    unsigned lo = f32_to_fp8_sw(a) | (f32_to_fp8_sw(b) << 8);
    return HI ? ((old & 0x0000FFFFu) | (lo << 16))
              : ((old & 0xFFFF0000u) | lo);
#endif
}

// decode 2 fp8 from low/high 16 bits of v
template <bool HI>
__device__ inline v2f dec_pair(unsigned v) {
#ifdef HAVE_HW_FP8_DEC
    return __builtin_amdgcn_cvt_pk_f32_fp8((int)v, HI);
#else
    unsigned h = HI ? (v >> 16) : (v & 0xFFFFu);
    v2f r; r.x = fp8_to_f32_sw(h & 0xFFu); r.y = fp8_to_f32_sw((h >> 8) & 0xFFu);
    return r;
#endif
}

// dot of 16 fp8 pairs held in two uint4
__device__ inline float dot16_fp8(const uint4& ua, const uint4& ub) {
    const unsigned* au = (const unsigned*)&ua;
    const unsigned* bu = (const unsigned*)&ub;
    float d = 0.f;
#pragma unroll
    for (int m = 0; m < 4; ++m) {
        v2f a0 = dec_pair<false>(au[m]);
        v2f a1 = dec_pair<true>(au[m]);
        v2f b0 = dec_pair<false>(bu[m]);
        v2f b1 = dec_pair<true>(bu[m]);
        d += a0.x * b0.x + a0.y * b0.y + a1.x * b1.x + a1.y * b1.y;
    }
    return d;
}

// ---------------------------------------------------------------------------
// Kernel 1: L2-normalize over channels (fp32 math), write transposed
// (B*N, D) fp8-e4m3 layout: one 128B row (= one cache line) per pixel.
// 256-thread block = 64 pixels x 4 channel-quarters, one pass.
// ---------------------------------------------------------------------------
__global__ void stego_normalize7(const float* __restrict__ feat,
                                 unsigned char* __restrict__ fnorm) {
    int lp = threadIdx.x & 63;        // pixel within block
    int q  = threadIdx.x >> 6;        // channel quarter 0..3
    int p  = blockIdx.x * 64 + lp;    // global pixel id (BN/64 = 512 blocks)
    int b  = p >> 12;                 // p / NPIX
    int n  = p & (NPIX - 1);
    const float* base = feat + ((size_t)b * DCH + q * 32) * NPIX + n;

    float vals[32];
    float s = 0.f;
#pragma unroll
    for (int d = 0; d < 32; ++d) {
        float v = base[(size_t)d * NPIX];   // lanes consecutive n -> coalesced
        vals[d] = v;
        s += v * v;
    }

    __shared__ float part[256];
    part[q * 64 + lp] = s;
    __syncthreads();
    float tot = part[lp] + part[64 + lp] + part[128 + lp] + part[192 + lp];
    float inv = 1.0f / fmaxf(sqrtf(tot), 1e-12f);

    unsigned pk[8];
#pragma unroll
    for (int k = 0; k < 8; ++k) {
        unsigned v = 0;
        v = enc_pair<false>(vals[4 * k + 0] * inv, vals[4 * k + 1] * inv, v);
        v = enc_pair<true>(vals[4 * k + 2] * inv, vals[4 * k + 3] * inv, v);
        pk[k] = v;
    }
    uint4* outp = (uint4*)(fnorm + (size_t)p * DCH + q * 32);
    outp[0] = make_uint4(pk[0], pk[1], pk[2], pk[3]);
    outp[1] = make_uint4(pk[4], pk[5], pk[6], pk[7]);
}

// ---------------------------------------------------------------------------
// Kernel 2: 8 lanes per pair, TWO pairs per lane-group -> 4 independent
// 16B gather loads in flight per thread (MLP). Per-block partial -> ws.
// NO fences / device-scope sync (R3: L2 invalidation, 4x) and NO
// same-address atomics (R7: 4096 serialized RMWs = 55us tail).
// ---------------------------------------------------------------------------
__global__ void stego_pair_loss7(const unsigned char* __restrict__ fnorm,
                                 const int* __restrict__ pb, const int* __restrict__ pi,
                                 const int* __restrict__ pj,
                                 const int* __restrict__ nb, const int* __restrict__ ni,
                                 const int* __restrict__ nj,
                                 float* __restrict__ partials, int P, float invP) {
    int t = blockIdx.x * blockDim.x + threadIdx.x;
    int g   = t >> 3;                 // pair group: handles pairs 2g, 2g+1
    int sub = t & 7;
    int pA = 2 * g, pB = 2 * g + 1;
    bool actA = (pA < 2 * P), actB = (pB < 2 * P);
    float sgnA = 1.f, sgnB = 1.f;

    const uint4 *vaA = nullptr, *vbA = nullptr, *vaB = nullptr, *vbB = nullptr;
    if (actA) {
        int b, i, j;
        if (pA < P) { b = pb[pA]; i = pi[pA]; j = pj[pA]; sgnA = -1.f; }
        else { int u = pA - P; b = nb[u]; i = ni[u]; j = nj[u]; }
        vaA = (const uint4*)(fnorm + ((size_t)b * NPIX + i) * DCH);
        vbA = (const uint4*)(fnorm + ((size_t)b * NPIX + j) * DCH);
    }
    if (actB) {
        int b, i, j;
        if (pB < P) { b = pb[pB]; i = pi[pB]; j = pj[pB]; sgnB = -1.f; }
        else { int u = pB - P; b = nb[u]; i = ni[u]; j = nj[u]; }
        vaB = (const uint4*)(fnorm + ((size_t)b * NPIX + i) * DCH);
        vbB = (const uint4*)(fnorm + ((size_t)b * NPIX + j) * DCH);
    }

    float dotA = 0.f, dotB = 0.f;
    if (actA & actB) {
        // common case: issue all 4 loads back-to-back, then consume
        uint4 a0 = vaA[sub], b0 = vbA[sub], a1 = vaB[sub], b1 = vbB[sub];
        dotA = dot16_fp8(a0, b0);
        dotB = dot16_fp8(a1, b1);
    } else if (actA) {
        uint4 a0 = vaA[sub], b0 = vbA[sub];
        dotA = dot16_fp8(a0, b0);
    }

    // reduce each dot across the 8 lanes of this group
    dotA += __shfl_xor(dotA, 4, 64);
    dotA += __shfl_xor(dotA, 2, 64);
    dotA += __shfl_xor(dotA, 1, 64);
    dotB += __shfl_xor(dotB, 4, 64);
    dotB += __shfl_xor(dotB, 2, 64);
    dotB += __shfl_xor(dotB, 1, 64);

    float loss = 0.f;
    if (sub == 0) {
        if (actA) {
            float z = sgnA * dotA * 10.0f;                        // /TEMPERATURE
            loss += (fmaxf(z, 0.f) + log1pf(expf(-fabsf(z)))) * invP;
        }
        if (actB) {
            float z = sgnB * dotB * 10.0f;
            loss += (fmaxf(z, 0.f) + log1pf(expf(-fabsf(z)))) * invP;
        }
    }
    // loss nonzero only on lanes 0,8,...,56
    loss += __shfl_xor(loss, 8, 64);
    loss += __shfl_xor(loss, 16, 64);
    loss += __shfl_xor(loss, 32, 64);

    __shared__ float red[4];
    int lane = threadIdx.x & 63;
    int wave = threadIdx.x >> 6;
    if (lane == 0) red[wave] = loss;
    __syncthreads();
    if (threadIdx.x == 0)
        partials[blockIdx.x] = red[0] + red[1] + red[2] + red[3];
}

// ---------------------------------------------------------------------------
// Kernel 3: final deterministic reduce of per-block partials -> d_out.
// ---------------------------------------------------------------------------
__global__ void stego_reduce7(const float* __restrict__ partials,
                              float* __restrict__ out, int nPart) {
    float s = 0.f;
    for (int idx = threadIdx.x; idx < nPart; idx += blockDim.x)
        s += partials[idx];
    for (int off = 32; off > 0; off >>= 1)
        s += __shfl_down(s, off, 64);
    __shared__ float red[4];
    if ((threadIdx.x & 63) == 0) red[threadIdx.x >> 6] = s;
    __syncthreads();
    if (threadIdx.x == 0) out[0] = red[0] + red[1] + red[2] + red[3];
}

// ---------------------------------------------------------------------------
// Fallback (ws too small): invnorm-only + strided gathers + atomics.
// ---------------------------------------------------------------------------
__global__ void stego_invnorm(const float* __restrict__ feat,
                              float* __restrict__ invn, int bn) {
    int p = blockIdx.x * blockDim.x + threadIdx.x;
    if (p >= bn) return;
    int b = p / NPIX;
    int n = p - b * NPIX;
    const float* base = feat + (size_t)b * DCH * NPIX + n;
    float sum = 0.f;
#pragma unroll 8
    for (int d = 0; d < DCH; ++d) {
        float v = base[(size_t)d * NPIX];
        sum += v * v;
    }
    invn[p] = 1.0f / fmaxf(sqrtf(sum), 1e-12f);
}

__global__ void stego_pair_loss_strided(const float* __restrict__ feat,
                                        const float* __restrict__ invn,
                                        const int* __restrict__ pb, const int* __restrict__ pi,
                                        const int* __restrict__ pj,
                                        const int* __restrict__ nb, const int* __restrict__ ni,
                                        const int* __restrict__ nj,
                                        float* __restrict__ out, int P, float invP) {
    int t = blockIdx.x * blockDim.x + threadIdx.x;
    float loss = 0.f;
    if (t < 2 * P) {
        int b, i, j;
        float sgn;
        if (t < P) { b = pb[t]; i = pi[t]; j = pj[t]; sgn = -1.f; }
        else { int u = t - P; b = nb[u]; i = ni[u]; j = nj[u]; sgn = 1.f; }
        const float* a = feat + (size_t)b * DCH * NPIX + i;
        const float* c = feat + (size_t)b * DCH * NPIX + j;
        float dot = 0.f;
#pragma unroll 8
        for (int d = 0; d < DCH; ++d)
            dot += a[(size_t)d * NPIX] * c[(size_t)d * NPIX];
        dot *= invn[b * NPIX + i] * invn[b * NPIX + j];
        float z = sgn * dot * 10.0f;
        float sp = fmaxf(z, 0.f) + log1pf(expf(-fabsf(z)));
        loss = sp * invP;
    }
    for (int off = 32; off > 0; off >>= 1)
        loss += __shfl_down(loss, off, 64);
    __shared__ float red[4];
    int lane = threadIdx.x & 63;
    int wave = threadIdx.x >> 6;
    if (lane == 0) red[wave] = loss;
    __syncthreads();
    if (threadIdx.x == 0) {
        float s = red[0] + red[1] + red[2] + red[3];
        atomicAdd(out, s);
    }
}

extern "C" void kernel_launch(void* const* d_in, const int* in_sizes, int n_in,
                              void* d_out, int out_size, void* d_ws, size_t ws_size,
                              hipStream_t stream) {
    const float* feat = (const float*)d_in[0];
    const int* pb = (const int*)d_in[1];
    const int* pi = (const int*)d_in[2];
    const int* pj = (const int*)d_in[3];
    const int* nb = (const int*)d_in[4];
    const int* ni = (const int*)d_in[5];
    const int* nj = (const int*)d_in[6];
    float* out = (float*)d_out;

    const int P = in_sizes[1];
    const float invP = 1.0f / (float)P;

    size_t fnorm_bytes = (size_t)BN * DCH;                    // 4 MB fp8
    int nGroups = P;                                          // 2P pairs / 2 per group
    int pairThreads = nGroups * 8;
    int pairBlocks = (pairThreads + 255) / 256;               // 2048 for P=65536
    size_t need = fnorm_bytes + (size_t)pairBlocks * sizeof(float);

    if (ws_size >= need) {
        unsigned char* fnorm = (unsigned char*)d_ws;
        float* partials = (float*)((char*)d_ws + fnorm_bytes);
        stego_normalize7<<<BN / 64, 256, 0, stream>>>(feat, fnorm);
        stego_pair_loss7<<<pairBlocks, 256, 0, stream>>>(
            fnorm, pb, pi, pj, nb, ni, nj, partials, P, invP);
        stego_reduce7<<<1, 256, 0, stream>>>(partials, out, pairBlocks);
    } else {
        (void)hipMemsetAsync(d_out, 0, sizeof(float), stream);
        float* invn = (float*)d_ws;  // BN floats = 128 KB
        stego_invnorm<<<(BN + 255) / 256, 256, 0, stream>>>(feat, invn, BN);
        int total = 2 * P;
        stego_pair_loss_strided<<<(total + 255) / 256, 256, 0, stream>>>(
            feat, invn, pb, pi, pj, nb, ni, nj, out, P, invP);
    }
}

// Round 9
// 87.371 us; speedup vs baseline: 1.5316x; 1.0146x over previous
//
#include <hip/hip_runtime.h>
#include <math.h>

#define DCH  128    // channel dim
#define NPIX 4096   // H*W
#define BATCH 8
#define BN   (BATCH * NPIX)

typedef float v2f __attribute__((ext_vector_type(2)));

// ---------------------------------------------------------------------------
// OCP e4m3fn helpers: HW cvt on gfx950, exact software fallback otherwise.
// The builtins' word-select args must be COMPILE-TIME constants -> template.
// ---------------------------------------------------------------------------
#if __has_builtin(__builtin_amdgcn_cvt_pk_fp8_f32)
#define HAVE_HW_FP8_ENC 1
#endif
#if __has_builtin(__builtin_amdgcn_cvt_pk_f32_fp8)
#define HAVE_HW_FP8_DEC 1
#endif

__device__ inline unsigned f32_to_fp8_sw(float x) {
    unsigned s = (__float_as_uint(x) >> 24) & 0x80u;
    float ax = fabsf(x);
    if (!(ax > 0.f)) return s;
    if (ax >= 448.f) return s | 0x7Eu;
    int e; frexpf(ax, &e);                       // ax = m*2^e, m in [0.5,1)
    if (e >= -5) {                               // normal: 1.mmm * 2^(e-1)
        int q = (int)rintf(ldexpf(ax, 4 - e));   // in [8,16]
        if (q == 16) { q = 8; ++e; }
        if (e + 6 >= 16) return s | 0x7Eu;
        return s | ((unsigned)(e + 6) << 3) | (unsigned)(q - 8);
    } else {                                     // subnormal: m * 2^-9
        int q = (int)rintf(ldexpf(ax, 9));
        if (q >= 8) return s | (1u << 3);
        return s | (unsigned)q;
    }
}

__device__ inline float fp8_to_f32_sw(unsigned b) {
    unsigned s = b >> 7, e = (b >> 3) & 0xFu, m = b & 7u;
    float v = (e == 0) ? (float)m * 0.001953125f          // m * 2^-9
                       : ldexpf((float)(8u + m), (int)e - 10);
    return s ? -v : v;
}

// pack floats (a,b) as 2 fp8 into the low/high 16 bits of `old`
template <bool HI>
__device__ inline unsigned enc_pair(float a, float b, unsigned old) {
#ifdef HAVE_HW_FP8_ENC
    return (unsigned)__builtin_amdgcn_cvt_pk_fp8_f32(a, b, (int)old, HI);
#else
    unsigned lo = f32_to_fp8_sw(a) | (f32_to_fp8_sw(b) << 8);
    return HI ? ((old & 0x0000FFFFu) | (lo << 16))
              : ((old & 0xFFFF0000u) | lo);
#endif
}

// decode 2 fp8 from low/high 16 bits of v
template <bool HI>
__device__ inline v2f dec_pair(unsigned v) {
#ifdef HAVE_HW_FP8_DEC
    return __builtin_amdgcn_cvt_pk_f32_fp8((int)v, HI);
#else
    unsigned h = HI ? (v >> 16) : (v & 0xFFFFu);
    v2f r; r.x = fp8_to_f32_sw(h & 0xFFu); r.y = fp8_to_f32_sw((h >> 8) & 0xFFu);
    return r;
#endif
}

// dot of 16 fp8 pairs held in two uint4
__device__ inline float dot16_fp8(const uint4& ua, const uint4& ub) {
    const unsigned* au = (const unsigned*)&ua;
    const unsigned* bu = (const unsigned*)&ub;
    float d = 0.f;
#pragma unroll
    for (int m = 0; m < 4; ++m) {
        v2f a0 = dec_pair<false>(au[m]);
        v2f a1 = dec_pair<true>(au[m]);
        v2f b0 = dec_pair<false>(bu[m]);
        v2f b1 = dec_pair<true>(bu[m]);
        d += a0.x * b0.x + a0.y * b0.y + a1.x * b1.x + a1.y * b1.y;
    }
    return d;
}

// ---------------------------------------------------------------------------
// Kernel 1: L2-normalize over channels (fp32 math), write transposed
// (B*N, D) fp8-e4m3 layout: one 128B row (= one cache line) per pixel.
// 256-thread block = 64 pixels x 4 channel-quarters, one pass.
// ---------------------------------------------------------------------------
__global__ void stego_normalize8(const float* __restrict__ feat,
                                 unsigned char* __restrict__ fnorm) {
    int lp = threadIdx.x & 63;        // pixel within block
    int q  = threadIdx.x >> 6;        // channel quarter 0..3
    int p  = blockIdx.x * 64 + lp;    // global pixel id (BN/64 = 512 blocks)
    int b  = p >> 12;                 // p / NPIX
    int n  = p & (NPIX - 1);
    const float* base = feat + ((size_t)b * DCH + q * 32) * NPIX + n;

    float vals[32];
    float s = 0.f;
#pragma unroll
    for (int d = 0; d < 32; ++d) {
        float v = base[(size_t)d * NPIX];   // lanes consecutive n -> coalesced
        vals[d] = v;
        s += v * v;
    }

    __shared__ float part[256];
    part[q * 64 + lp] = s;
    __syncthreads();
    float tot = part[lp] + part[64 + lp] + part[128 + lp] + part[192 + lp];
    float inv = 1.0f / fmaxf(sqrtf(tot), 1e-12f);

    unsigned pk[8];
#pragma unroll
    for (int k = 0; k < 8; ++k) {
        unsigned v = 0;
        v = enc_pair<false>(vals[4 * k + 0] * inv, vals[4 * k + 1] * inv, v);
        v = enc_pair<true>(vals[4 * k + 2] * inv, vals[4 * k + 3] * inv, v);
        pk[k] = v;
    }
    uint4* outp = (uint4*)(fnorm + (size_t)p * DCH + q * 32);
    outp[0] = make_uint4(pk[0], pk[1], pk[2], pk[3]);
    outp[1] = make_uint4(pk[4], pk[5], pk[6], pk[7]);
}

// ---------------------------------------------------------------------------
// Kernel 2: 8 lanes per pair, FOUR pairs per lane-group -> 8 independent
// 16B gather loads in flight per lane (max MLP before VGPR pressure).
// Per-block partial -> ws. NO device-scope fences (R3: per-XCD L2
// invalidation, 4x) and NO same-address atomics (R7: 4096 RMWs = 55us).
// ---------------------------------------------------------------------------
__global__ void stego_pair_loss8(const unsigned char* __restrict__ fnorm,
                                 const int* __restrict__ pb, const int* __restrict__ pi,
                                 const int* __restrict__ pj,
                                 const int* __restrict__ nb, const int* __restrict__ ni,
                                 const int* __restrict__ nj,
                                 float* __restrict__ partials, int P, float invP) {
    int t = blockIdx.x * blockDim.x + threadIdx.x;
    int g   = t >> 3;                 // group: handles pairs 4g .. 4g+3
    int sub = t & 7;

    float dot[4] = {0.f, 0.f, 0.f, 0.f};
    float sgn[4] = {1.f, 1.f, 1.f, 1.f};
    bool  act[4];
    const uint4 *va[4], *vb[4];
#pragma unroll
    for (int k = 0; k < 4; ++k) {
        int pr = 4 * g + k;
        act[k] = (pr < 2 * P);
        va[k] = vb[k] = nullptr;
        if (act[k]) {
            int b, i, j;
            if (pr < P) { b = pb[pr]; i = pi[pr]; j = pj[pr]; sgn[k] = -1.f; }
            else { int u = pr - P; b = nb[u]; i = ni[u]; j = nj[u]; }
            va[k] = (const uint4*)(fnorm + ((size_t)b * NPIX + i) * DCH);
            vb[k] = (const uint4*)(fnorm + ((size_t)b * NPIX + j) * DCH);
        }
    }

    if (act[0] & act[1] & act[2] & act[3]) {
        // common case: 8 independent loads issued back-to-back, then consume
        uint4 a0 = va[0][sub], b0 = vb[0][sub];
        uint4 a1 = va[1][sub], b1 = vb[1][sub];
        uint4 a2 = va[2][sub], b2 = vb[2][sub];
        uint4 a3 = va[3][sub], b3 = vb[3][sub];
        dot[0] = dot16_fp8(a0, b0);
        dot[1] = dot16_fp8(a1, b1);
        dot[2] = dot16_fp8(a2, b2);
        dot[3] = dot16_fp8(a3, b3);
    } else {
#pragma unroll
        for (int k = 0; k < 4; ++k)
            if (act[k]) {
                uint4 a = va[k][sub], b = vb[k][sub];
                dot[k] = dot16_fp8(a, b);
            }
    }

    float loss = 0.f;
#pragma unroll
    for (int k = 0; k < 4; ++k) {
        dot[k] += __shfl_xor(dot[k], 4, 64);
        dot[k] += __shfl_xor(dot[k], 2, 64);
        dot[k] += __shfl_xor(dot[k], 1, 64);
        if (sub == 0 && act[k]) {
            float z = sgn[k] * dot[k] * 10.0f;                    // /TEMPERATURE
            loss += (fmaxf(z, 0.f) + log1pf(expf(-fabsf(z)))) * invP;
        }
    }
    // loss nonzero only on lanes 0,8,...,56
    loss += __shfl_xor(loss, 8, 64);
    loss += __shfl_xor(loss, 16, 64);
    loss += __shfl_xor(loss, 32, 64);

    __shared__ float red[4];
    int lane = threadIdx.x & 63;
    int wave = threadIdx.x >> 6;
    if (lane == 0) red[wave] = loss;
    __syncthreads();
    if (threadIdx.x == 0)
        partials[blockIdx.x] = red[0] + red[1] + red[2] + red[3];
}

// ---------------------------------------------------------------------------
// Kernel 3: final deterministic reduce of per-block partials -> d_out.
// ---------------------------------------------------------------------------
__global__ void stego_reduce8(const float* __restrict__ partials,
                              float* __restrict__ out, int nPart) {
    float s = 0.f;
    for (int idx = threadIdx.x; idx < nPart; idx += blockDim.x)
        s += partials[idx];
    for (int off = 32; off > 0; off >>= 1)
        s += __shfl_down(s, off, 64);
    __shared__ float red[4];
    if ((threadIdx.x & 63) == 0) red[threadIdx.x >> 6] = s;
    __syncthreads();
    if (threadIdx.x == 0) out[0] = red[0] + red[1] + red[2] + red[3];
}

// ---------------------------------------------------------------------------
// Fallback (ws too small): invnorm-only + strided gathers + atomics.
// ---------------------------------------------------------------------------
__global__ void stego_invnorm(const float* __restrict__ feat,
                              float* __restrict__ invn, int bn) {
    int p = blockIdx.x * blockDim.x + threadIdx.x;
    if (p >= bn) return;
    int b = p / NPIX;
    int n = p - b * NPIX;
    const float* base = feat + (size_t)b * DCH * NPIX + n;
    float sum = 0.f;
#pragma unroll 8
    for (int d = 0; d < DCH; ++d) {
        float v = base[(size_t)d * NPIX];
        sum += v * v;
    }
    invn[p] = 1.0f / fmaxf(sqrtf(sum), 1e-12f);
}

__global__ void stego_pair_loss_strided(const float* __restrict__ feat,
                                        const float* __restrict__ invn,
                                        const int* __restrict__ pb, const int* __restrict__ pi,
                                        const int* __restrict__ pj,
                                        const int* __restrict__ nb, const int* __restrict__ ni,
                                        const int* __restrict__ nj,
                                        float* __restrict__ out, int P, float invP) {
    int t = blockIdx.x * blockDim.x + threadIdx.x;
    float loss = 0.f;
    if (t < 2 * P) {
        int b, i, j;
        float sgn;
        if (t < P) { b = pb[t]; i = pi[t]; j = pj[t]; sgn = -1.f; }
        else { int u = t - P; b = nb[u]; i = ni[u]; j = nj[u]; sgn = 1.f; }
        const float* a = feat + (size_t)b * DCH * NPIX + i;
        const float* c = feat + (size_t)b * DCH * NPIX + j;
        float dot = 0.f;
#pragma unroll 8
        for (int d = 0; d < DCH; ++d)
            dot += a[(size_t)d * NPIX] * c[(size_t)d * NPIX];
        dot *= invn[b * NPIX + i] * invn[b * NPIX + j];
        float z = sgn * dot * 10.0f;
        float sp = fmaxf(z, 0.f) + log1pf(expf(-fabsf(z)));
        loss = sp * invP;
    }
    for (int off = 32; off > 0; off >>= 1)
        loss += __shfl_down(loss, off, 64);
    __shared__ float red[4];
    int lane = threadIdx.x & 63;
    int wave = threadIdx.x >> 6;
    if (lane == 0) red[wave] = loss;
    __syncthreads();
    if (threadIdx.x == 0) {
        float s = red[0] + red[1] + red[2] + red[3];
        atomicAdd(out, s);
    }
}

extern "C" void kernel_launch(void* const* d_in, const int* in_sizes, int n_in,
                              void* d_out, int out_size, void* d_ws, size_t ws_size,
                              hipStream_t stream) {
    const float* feat = (const float*)d_in[0];
    const int* pb = (const int*)d_in[1];
    const int* pi = (const int*)d_in[2];
    const int* pj = (const int*)d_in[3];
    const int* nb = (const int*)d_in[4];
    const int* ni = (const int*)d_in[5];
    const int* nj = (const int*)d_in[6];
    float* out = (float*)d_out;

    const int P = in_sizes[1];
    const float invP = 1.0f / (float)P;

    size_t fnorm_bytes = (size_t)BN * DCH;                    // 4 MB fp8
    int nGroups = (2 * P + 3) / 4;                            // 4 pairs per group
    int pairThreads = nGroups * 8;
    int pairBlocks = (pairThreads + 255) / 256;               // 1024 for P=65536
    size_t need = fnorm_bytes + (size_t)pairBlocks * sizeof(float);

    if (ws_size >= need) {
        unsigned char* fnorm = (unsigned char*)d_ws;
        float* partials = (float*)((char*)d_ws + fnorm_bytes);
        stego_normalize8<<<BN / 64, 256, 0, stream>>>(feat, fnorm);
        stego_pair_loss8<<<pairBlocks, 256, 0, stream>>>(
            fnorm, pb, pi, pj, nb, ni, nj, partials, P, invP);
        stego_reduce8<<<1, 256, 0, stream>>>(partials, out, pairBlocks);
    } else {
        (void)hipMemsetAsync(d_out, 0, sizeof(float), stream);
        float* invn = (float*)d_ws;  // BN floats = 128 KB
        stego_invnorm<<<(BN + 255) / 256, 256, 0, stream>>>(feat, invn, BN);
        int total = 2 * P;
        stego_pair_loss_strided<<<(total + 255) / 256, 256, 0, stream>>>(
            feat, invn, pb, pi, pj, nb, ni, nj, out, P, invP);
    }
}